// Round 1
// baseline (271.600 us; speedup 1.0000x reference)
//
#include <hip/hip_runtime.h>
#include <hip/hip_bf16.h>
#include <cstdint>

// Problem constants (fixed by the reference).
#define CDIM   256      // channels == code dim
#define NCODES 256
#define HWB    32768    // H*W = 128*256
#define BATCH  4
#define BN     64       // pixels per block tile
#define BK     32       // K-chunk (one 16x16x32 MFMA deep)

typedef __bf16 bf16x8 __attribute__((ext_vector_type(8)));
typedef float  f32x4  __attribute__((ext_vector_type(4)));

// ---------------------------------------------------------------------------
// Kernel 1: inv_norm[n] = 1 / sum_c codebook[n][c]^2.  One wave per code row.
// ---------------------------------------------------------------------------
__global__ void norms_kernel(const float* __restrict__ cb, float* __restrict__ inv_norm) {
    const int n = blockIdx.x;
    const int lane = threadIdx.x;   // 64 threads
    const float* row = cb + n * CDIM;
    float s = 0.f;
#pragma unroll
    for (int c = 0; c < CDIM; c += 64) {
        float v = row[c + lane];
        s += v * v;
    }
#pragma unroll
    for (int off = 32; off > 0; off >>= 1) s += __shfl_down(s, off, 64);
    if (lane == 0) inv_norm[n] = 1.0f / s;
}

// ---------------------------------------------------------------------------
// Kernel 2: M[i][j] = sum_n cb[n][i] * inv_norm[n] * cb[n][j], stored bf16
// row-major [256][256].  i is block-uniform -> cb[n*C+i] & inv_norm[n] become
// scalar loads; cb[n*C+j] is coalesced across the block.
// ---------------------------------------------------------------------------
__global__ void mmat_kernel(const float* __restrict__ cb, const float* __restrict__ inv_norm,
                            __bf16* __restrict__ Mb) {
    const int i = blockIdx.x;
    const int j = threadIdx.x;
    float acc = 0.f;
#pragma unroll 4
    for (int n = 0; n < NCODES; ++n) {
        acc += (cb[n * CDIM + i] * inv_norm[n]) * cb[n * CDIM + j];
    }
    Mb[i * CDIM + j] = (__bf16)acc;
}

// ---------------------------------------------------------------------------
// Kernel 3: out[b,c,p] = sum_k M[c][k] * feat[b,k,p].
// GEMM: A = M (256x256 bf16, L2-resident), B = feature (256 x 32768 fp32 per
// batch), C = out fp32.  Block = 256 threads (4 waves), tile = 256(c) x 64(p),
// so the feature K-strip is read from HBM exactly once.
// Per wave: 64 rows x 64 px = 4x4 tiles of 16x16, K-loop 8 chunks of 32.
// ---------------------------------------------------------------------------
__global__ __launch_bounds__(256, 4) void recon_kernel(
    const float* __restrict__ feat, const __bf16* __restrict__ Mb,
    float* __restrict__ out) {
    // A tile: [m][k] row-major, 256 x 32 bf16 (rows = 64B -> 16B-aligned frags)
    __shared__ __align__(16) __bf16 Alds[CDIM * BK];   // 16 KB
    // B tile stored transposed: [p][k] row-major, 64 x 32 bf16
    __shared__ __align__(16) __bf16 Blds[BN * BK];     // 4 KB

    const int tid  = threadIdx.x;
    const int lane = tid & 63;
    const int w    = tid >> 6;       // wave 0..3
    const int quad = lane >> 4;      // 0..3
    const int l16  = lane & 15;

    const int b  = blockIdx.y;
    const int p0 = blockIdx.x * BN;

    const float* fbase = feat + ((size_t)b * CDIM) * HWB + p0;
    float*       obase = out  + ((size_t)b * CDIM) * HWB + p0;

    f32x4 acc[4][4];
#pragma unroll
    for (int mt = 0; mt < 4; ++mt)
#pragma unroll
        for (int nt = 0; nt < 4; ++nt)
            acc[mt][nt] = (f32x4){0.f, 0.f, 0.f, 0.f};

    // B staging mapping: thread -> p_local = lane, k_local = w*8 + j.
    // Global loads are dword, coalesced along p (64 consecutive floats/wave).
    const float* fp = fbase + (size_t)(w * 8) * HWB + lane;

    for (int kc = 0; kc < 8; ++kc) {
        // ---- B: global fp32 -> regs (issue first so A-async can overlap) ----
        float fv[8];
#pragma unroll
        for (int j = 0; j < 8; ++j)
            fv[j] = fp[(size_t)j * HWB];

        // ---- A: async global->LDS, bf16, 16B/lane granules -----------------
        // granule g = gbase + lane; LDS gets granule g at byte offset g*16;
        // global source = row (g>>2), k-subchunk (g&3) of this K-chunk.
#pragma unroll
        for (int j = 0; j < 4; ++j) {
            const int gbase = j * 256 + (w << 6);          // wave-uniform
            const int g = gbase + lane;                    // per-lane granule
            const __bf16* gsrc = Mb + (g >> 2) * CDIM + kc * BK + (g & 3) * 8;
            __builtin_amdgcn_global_load_lds(
                (const __attribute__((address_space(1))) void*)gsrc,
                (__attribute__((address_space(3))) void*)(Alds + (size_t)gbase * 8),
                16, 0, 0);
        }

        // ---- B: convert to bf16, write transposed tile ---------------------
        bf16x8 pk;
#pragma unroll
        for (int j = 0; j < 8; ++j) pk[j] = (__bf16)fv[j];
        *(bf16x8*)(Blds + lane * BK + w * 8) = pk;

        __syncthreads();   // drains vmcnt(0): A-async + lgkm all complete

        // ---- MFMA: a_frag A[m=l16][k=quad*8+j], b_frag = B^T rows ----------
        bf16x8 bfr[4];
#pragma unroll
        for (int nt = 0; nt < 4; ++nt)
            bfr[nt] = *(const bf16x8*)(Blds + (nt * 16 + l16) * BK + quad * 8);
#pragma unroll
        for (int mt = 0; mt < 4; ++mt) {
            bf16x8 af = *(const bf16x8*)(Alds + (w * 64 + mt * 16 + l16) * BK + quad * 8);
#pragma unroll
            for (int nt = 0; nt < 4; ++nt)
                acc[mt][nt] = __builtin_amdgcn_mfma_f32_16x16x32_bf16(
                    af, bfr[nt], acc[mt][nt], 0, 0, 0);
        }
        __syncthreads();   // before next iteration overwrites tiles
        fp += (size_t)BK * HWB;
    }

    // ---- Epilogue: D[row=quad*4+r][col=l16] per 16x16 tile -----------------
#pragma unroll
    for (int mt = 0; mt < 4; ++mt) {
#pragma unroll
        for (int r = 0; r < 4; ++r) {
            const int c = w * 64 + mt * 16 + quad * 4 + r;
            float* orow = obase + (size_t)c * HWB + l16;
#pragma unroll
            for (int nt = 0; nt < 4; ++nt)
                orow[nt * 16] = acc[mt][nt][r];
        }
    }
}

// ---------------------------------------------------------------------------
extern "C" void kernel_launch(void* const* d_in, const int* in_sizes, int n_in,
                              void* d_out, int out_size, void* d_ws, size_t ws_size,
                              hipStream_t stream) {
    const float* feat = (const float*)d_in[0];   // [4,256,128,256] fp32
    const float* cb   = (const float*)d_in[1];   // [256,256] fp32
    float* out = (float*)d_out;

    float*  inv_norm = (float*)d_ws;                       // 1 KB
    __bf16* Mb       = (__bf16*)((char*)d_ws + 1024);      // 128 KB bf16 M

    norms_kernel<<<NCODES, 64, 0, stream>>>(cb, inv_norm);
    mmat_kernel<<<NCODES, CDIM, 0, stream>>>(cb, inv_norm, Mb);

    dim3 grid(HWB / BN, BATCH);   // 512 x 4 blocks
    recon_kernel<<<grid, 256, 0, stream>>>(feat, Mb, out);
}